// Round 1
// baseline (581.579 us; speedup 1.0000x reference)
//
#include <hip/hip_runtime.h>

typedef float v2 __attribute__((ext_vector_type(2)));
typedef float v4 __attribute__((ext_vector_type(4)));

#define B_TOT 2048
#define T_STEPS 512
// D = 8, M = 2

// out layout (flat floats):
//   means: [B,T,8]    at 0
//   covs : [B,T,8,8]  at 8388608
//   Rs   : [B,T,2,2]  at 75497472
//   Hs   : [B,T,2,8]  at 79691776
#define OFF_COVS 8388608
#define OFF_RS   75497472
#define OFF_HS   79691776

__launch_bounds__(64, 1)
__global__ void kf_kernel(const float* __restrict__ input,
                          const float* __restrict__ mean0,
                          const float* __restrict__ cov0,
                          const float* __restrict__ Fm,
                          const float* __restrict__ Hm,
                          const float* __restrict__ Qm,
                          const float* __restrict__ Rm,
                          float* __restrict__ out)
{
    // LDS: staged input + per-group gather scratch (padded strides vs bank conflicts)
    __shared__ float xs[8 * 1024];      // 8 groups x (T*M) floats = 32 KB
    __shared__ float hp0_s[8 * 12];
    __shared__ float hp1_s[8 * 12];
    __shared__ float mean_s[8 * 12];
    __shared__ float u_s[8 * 88];       // [g] + d*10 + writer_lane

    const int lane = threadIdx.x;       // 0..63
    const int g = lane >> 3;            // group within block
    const int j = lane & 7;             // row index
    const int b0 = blockIdx.x * 8;
    const int b = b0 + g;

    // ---- stage this block's input rows (8 groups x 1024 floats, contiguous) ----
    {
        const v4* src = (const v4*)(input + (size_t)b0 * 1024);
        v4* dst = (v4*)xs;
        #pragma unroll
        for (int i = 0; i < 32; ++i)
            dst[i * 64 + lane] = src[i * 64 + lane];
    }

    // ---- replicated constants ----
    // Fcol2[f][d2] = { F[2*d2, f], F[2*d2+1, f] }  (serves both F*X and X*F^T)
    v2 Fcol2[8][4];
    #pragma unroll
    for (int f = 0; f < 8; ++f)
        #pragma unroll
        for (int d2 = 0; d2 < 4; ++d2) {
            v2 t; t.x = Fm[(2 * d2) * 8 + f]; t.y = Fm[(2 * d2 + 1) * 8 + f];
            Fcol2[f][d2] = t;
        }
    v2 Frowj[4];                        // row j of F, pairs over columns
    #pragma unroll
    for (int d2 = 0; d2 < 4; ++d2) {
        v2 t; t.x = Fm[j * 8 + 2 * d2]; t.y = Fm[j * 8 + 2 * d2 + 1];
        Frowj[d2] = t;
    }
    v2 Hrow2[2][4];
    #pragma unroll
    for (int m = 0; m < 2; ++m)
        #pragma unroll
        for (int d2 = 0; d2 < 4; ++d2) {
            v2 t; t.x = Hm[m * 8 + 2 * d2]; t.y = Hm[m * 8 + 2 * d2 + 1];
            Hrow2[m][d2] = t;
        }
    v2 HFrow2[2][4];                    // HF = H @ F
    #pragma unroll
    for (int m = 0; m < 2; ++m)
        #pragma unroll
        for (int d2 = 0; d2 < 4; ++d2) {
            float a = 0.f, c = 0.f;
            #pragma unroll
            for (int k = 0; k < 8; ++k) {
                a += Hm[m * 8 + k] * Fm[k * 8 + 2 * d2];
                c += Hm[m * 8 + k] * Fm[k * 8 + 2 * d2 + 1];
            }
            v2 t; t.x = a; t.y = c; HFrow2[m][d2] = t;
        }
    v2 Qrow2[4];
    #pragma unroll
    for (int e2 = 0; e2 < 4; ++e2) {
        v2 t; t.x = Qm[j * 8 + 2 * e2]; t.y = Qm[j * 8 + 2 * e2 + 1];
        Qrow2[e2] = t;
    }
    const float r00 = Rm[0], r01 = Rm[1], r10 = Rm[2], r11 = Rm[3];
    const float Rval = (j == 0) ? r00 : (j == 1) ? r01 : (j == 2) ? r10 : r11;
    v2 Hflat; Hflat.x = Hm[2 * j]; Hflat.y = Hm[2 * j + 1];   // Hs output chunk

    // ---- state: row j of P, mean[j] ----
    v2 P2[4];
    {
        const v4* c4 = (const v4*)(cov0 + (size_t)b * 64 + j * 8);
        v4 a = c4[0], bb = c4[1];
        P2[0].x = a.x;  P2[0].y = a.y;  P2[1].x = a.z;  P2[1].y = a.w;
        P2[2].x = bb.x; P2[2].y = bb.y; P2[3].x = bb.z; P2[3].y = bb.w;
    }
    float mean_j = mean0[(size_t)b * 8 + j];

    // initial hm = H @ mean  (gather mean through LDS)
    float hm0, hm1;
    mean_s[g * 12 + j] = mean_j;
    __syncthreads();
    {
        const v4* ms = (const v4*)(mean_s + g * 12);
        v4 a = ms[0], bb = ms[1];
        v2 mu[4];
        mu[0].x = a.x;  mu[0].y = a.y;  mu[1].x = a.z;  mu[1].y = a.w;
        mu[2].x = bb.x; mu[2].y = bb.y; mu[3].x = bb.z; mu[3].y = bb.w;
        v2 t0 = {0.f, 0.f}, t1 = {0.f, 0.f};
        #pragma unroll
        for (int d2 = 0; d2 < 4; ++d2) { t0 += Hrow2[0][d2] * mu[d2]; t1 += Hrow2[1][d2] * mu[d2]; }
        hm0 = t0.x + t0.y; hm1 = t1.x + t1.y;
    }

    // ---- output pointers ----
    float* means_p = out + (size_t)b * T_STEPS * 8 + j;
    float* covs_p  = out + OFF_COVS + (size_t)b * T_STEPS * 64 + j * 8;
    float* Rs_p    = out + OFF_RS + (size_t)b * T_STEPS * 4 + j;    // j < 4 only
    float* Hs_p    = out + OFF_HS + (size_t)b * T_STEPS * 16 + 2 * j;
    const v2* xv   = (const v2*)(xs + g * 1024);

    for (int t = 0; t < T_STEPS; ++t) {
        // ---- emit prior state (output at t is pre-update state) ----
        means_p[0] = mean_j;
        {
            v4 cva, cvb;
            cva.x = P2[0].x; cva.y = P2[0].y; cva.z = P2[1].x; cva.w = P2[1].y;
            cvb.x = P2[2].x; cvb.y = P2[2].y; cvb.z = P2[3].x; cvb.w = P2[3].y;
            ((v4*)covs_p)[0] = cva;
            ((v4*)covs_p)[1] = cvb;
        }
        if (j < 4) Rs_p[0] = Rval;
        *((v2*)Hs_p) = Hflat;
        means_p += 8; covs_p += 64; Rs_p += 4; Hs_p += 16;

        // ---- hp[m] = HP[m, j] = H_row_m . P_row_j (symmetry makes it local) ----
        v2 a0 = {0.f, 0.f}, a1 = {0.f, 0.f};
        #pragma unroll
        for (int d2 = 0; d2 < 4; ++d2) { a0 += Hrow2[0][d2] * P2[d2]; a1 += Hrow2[1][d2] * P2[d2]; }
        const float hp0 = a0.x + a0.y;
        const float hp1 = a1.x + a1.y;
        hp0_s[g * 12 + j] = hp0;
        hp1_s[g * 12 + j] = hp1;
        __syncthreads();

        // gather full HP rows (over columns f)
        v2 hpa0[4], hpa1[4];
        {
            const v2* p0 = (const v2*)(hp0_s + g * 12);
            const v2* p1 = (const v2*)(hp1_s + g * 12);
            #pragma unroll
            for (int f2 = 0; f2 < 4; ++f2) { hpa0[f2] = p0[f2]; hpa1[f2] = p1[f2]; }
        }

        // ---- S = HP H^T + R (2x2), closed-form inverse ----
        v2 s00v = {0.f, 0.f}, s01v = {0.f, 0.f}, s11v = {0.f, 0.f};
        #pragma unroll
        for (int f2 = 0; f2 < 4; ++f2) {
            s00v += hpa0[f2] * Hrow2[0][f2];
            s01v += hpa0[f2] * Hrow2[1][f2];
            s11v += hpa1[f2] * Hrow2[1][f2];
        }
        const float s00 = s00v.x + s00v.y + r00;
        const float s01 = s01v.x + s01v.y + r01;
        const float s11 = s11v.x + s11v.y + r11;
        const float det = s00 * s11 - s01 * s01;
        const float idet = __builtin_amdgcn_rcpf(det);
        const float i00 = s11 * idet, i01 = -s01 * idet, i11 = s00 * idet;
        const float kt0 = i00 * hp0 + i01 * hp1;    // Kt[0, j]
        const float kt1 = i01 * hp0 + i11 * hp1;    // Kt[1, j]

        // ---- residual & mean update ----
        const v2 x = xv[t];
        const float rs0 = x.x - hm0;
        const float rs1 = x.y - hm1;
        const float mean_u = mean_j + kt0 * rs0 + kt1 * rs1;

        // ---- cov_u row j = P_row_j - kt0*HP[0,:] - kt1*HP[1,:] ----
        v2 cu[4];
        {
            v2 k0; k0.x = kt0; k0.y = kt0;
            v2 k1; k1.x = kt1; k1.y = kt1;
            #pragma unroll
            for (int f2 = 0; f2 < 4; ++f2)
                cu[f2] = P2[f2] - k0 * hpa0[f2] - k1 * hpa1[f2];
        }

        // ---- U = F * cov_u, column j (local 64-FMA matvec, packed) ----
        v2 u2[4] = {{0.f, 0.f}, {0.f, 0.f}, {0.f, 0.f}, {0.f, 0.f}};
        #pragma unroll
        for (int f = 0; f < 8; ++f) {
            const float cuf = (f & 1) ? cu[f >> 1].y : cu[f >> 1].x;
            v2 c; c.x = cuf; c.y = cuf;
            #pragma unroll
            for (int d2 = 0; d2 < 4; ++d2) u2[d2] += Fcol2[f][d2] * c;
        }

        // ---- LDS transpose of U + mean_u gather ----
        mean_s[g * 12 + j] = mean_u;
        #pragma unroll
        for (int d = 0; d < 8; ++d) {
            const float ud = (d & 1) ? u2[d >> 1].y : u2[d >> 1].x;
            u_s[g * 88 + d * 10 + j] = ud;
        }
        __syncthreads();

        v2 ur[4];     // row j of U
        {
            const v2* up = (const v2*)(u_s + g * 88 + j * 10);
            #pragma unroll
            for (int f2 = 0; f2 < 4; ++f2) ur[f2] = up[f2];
        }
        v2 mu2[4];    // all of mean_u
        {
            const v4* ms = (const v4*)(mean_s + g * 12);
            v4 a = ms[0], bb = ms[1];
            mu2[0].x = a.x;  mu2[0].y = a.y;  mu2[1].x = a.z;  mu2[1].y = a.w;
            mu2[2].x = bb.x; mu2[2].y = bb.y; mu2[3].x = bb.z; mu2[3].y = bb.w;
        }

        // ---- cov_p row j = U_row_j * F^T + Q_row_j ----
        v2 Pn[4] = {Qrow2[0], Qrow2[1], Qrow2[2], Qrow2[3]};
        #pragma unroll
        for (int f = 0; f < 8; ++f) {
            const float uf = (f & 1) ? ur[f >> 1].y : ur[f >> 1].x;
            v2 c; c.x = uf; c.y = uf;
            #pragma unroll
            for (int e2 = 0; e2 < 4; ++e2) Pn[e2] += Fcol2[f][e2] * c;
        }
        P2[0] = Pn[0]; P2[1] = Pn[1]; P2[2] = Pn[2]; P2[3] = Pn[3];

        // ---- mean predict: mean_j = F[j,:].mean_u ; hm = (H F).mean_u ----
        v2 t0 = {0.f, 0.f}, t1 = {0.f, 0.f}, t2 = {0.f, 0.f};
        #pragma unroll
        for (int d2 = 0; d2 < 4; ++d2) {
            t0 += Frowj[d2] * mu2[d2];
            t1 += HFrow2[0][d2] * mu2[d2];
            t2 += HFrow2[1][d2] * mu2[d2];
        }
        mean_j = t0.x + t0.y;
        hm0 = t1.x + t1.y;
        hm1 = t2.x + t2.y;
    }
}

extern "C" void kernel_launch(void* const* d_in, const int* in_sizes, int n_in,
                              void* d_out, int out_size, void* d_ws, size_t ws_size,
                              hipStream_t stream) {
    const float* input = (const float*)d_in[0];
    const float* mean0 = (const float*)d_in[1];
    const float* cov0  = (const float*)d_in[2];
    const float* F     = (const float*)d_in[3];
    const float* H     = (const float*)d_in[4];
    const float* Q     = (const float*)d_in[5];
    const float* R     = (const float*)d_in[6];
    float* out = (float*)d_out;

    hipLaunchKernelGGL(kf_kernel, dim3(B_TOT / 8), dim3(64), 0, stream,
                       input, mean0, cov0, F, H, Q, R, out);
}